// Round 4
// baseline (382.415 us; speedup 1.0000x reference)
//
#include <hip/hip_runtime.h>
#include <math.h>

// Problem constants
#define B_N 65536
#define G_N 6
#define IN_N 512
#define F_N 256
#define O_N 18

// Sort constants
#define NB 256     // histogram blocks (B_N / 256)
#define CHUNK 256

// GEMM tiling: per-wave 64x64 register tile, no LDS, no barriers.
// Block = 64 sorted rows x 4 waves (each wave owns a 64-wide N slice).
#define TBM 64
#define MAXT 1030   // max grouped 64-row tiles: 65536/64 + G

typedef __bf16 bf16x8 __attribute__((ext_vector_type(8)));
typedef float f32x4 __attribute__((ext_vector_type(4)));

// ---- workspace layout (bytes) ----
#define WS_BC     0
#define WS_BOFF   8192
#define WS_NTILES 16448
#define WS_DESC   16512
#define WS_W1T    32768
#define WS_W2T    1605632
#define WS_PERM   2097152
#define WS_H1     4194304
#define WS_HF     37748736

__device__ __forceinline__ unsigned short f2bf(float f) {
    union { float f; unsigned u; } a; a.f = f;
    unsigned r = a.u + 0x7fffu + ((a.u >> 16) & 1u);
    return (unsigned short)(r >> 16);
}
__device__ __forceinline__ float bf2f(unsigned short h) {
    union { unsigned u; float f; } a; a.u = ((unsigned)h) << 16;
    return a.f;
}

// 8 fp32 (two uint4) -> bf16x8, round-half-up (add 0x8000, take hi16 via v_perm)
__device__ __forceinline__ bf16x8 cvt8(const uint4 u0, const uint4 u1) {
    uint4 r;
    r.x = __builtin_amdgcn_perm(u0.y + 0x8000u, u0.x + 0x8000u, 0x07060302u);
    r.y = __builtin_amdgcn_perm(u0.w + 0x8000u, u0.z + 0x8000u, 0x07060302u);
    r.z = __builtin_amdgcn_perm(u1.y + 0x8000u, u1.x + 0x8000u, 0x07060302u);
    r.w = __builtin_amdgcn_perm(u1.w + 0x8000u, u1.z + 0x8000u, 0x07060302u);
    union { uint4 u; bf16x8 b; } c; c.u = r;
    return c.b;
}

// ---------- sort: histogram ----------
__global__ void k_hist(const int* __restrict__ idx, int* __restrict__ bc) {
    __shared__ int cnt[G_N];
    int t = threadIdx.x;
    if (t < G_N) cnt[t] = 0;
    __syncthreads();
    int e = blockIdx.x * CHUNK + t;
    atomicAdd(&cnt[idx[e]], 1);
    __syncthreads();
    if (t < G_N) bc[blockIdx.x * G_N + t] = cnt[t];
}

// ---------- sort: prefix + tile descriptors (single block, parallel scan) ----------
__global__ void k_prefix(const int* __restrict__ bc, int* __restrict__ boff,
                         int* __restrict__ ntiles, int* __restrict__ desc) {
    __shared__ int sbc[NB * G_N];   // 6 KB
    __shared__ int tot[G_N], st[G_N];
    __shared__ int tstart[G_N + 1];
    int t = threadIdx.x;
    for (int i = t; i < NB * G_N; i += 256) sbc[i] = bc[i];
    __syncthreads();
    int w = t >> 6, l = t & 63;
    for (int g = w; g < G_N; g += 4) {
        int v[4]; int s = 0;
#pragma unroll
        for (int j = 0; j < 4; j++) { v[j] = sbc[(l * 4 + j) * G_N + g]; s += v[j]; }
        int inc = s;
#pragma unroll
        for (int o = 1; o < 64; o <<= 1) { int x = __shfl_up(inc, o, 64); if (l >= o) inc += x; }
        int run = inc - s;   // exclusive prefix
        if (l == 63) tot[g] = inc;
#pragma unroll
        for (int j = 0; j < 4; j++) { sbc[(l * 4 + j) * G_N + g] = run; run += v[j]; }
    }
    __syncthreads();
    if (t == 0) {
        int acc = 0;
        for (int g = 0; g < G_N; g++) { st[g] = acc; acc += tot[g]; }
        int nt = 0;
        for (int g = 0; g < G_N; g++) { tstart[g] = nt; nt += (tot[g] + TBM - 1) / TBM; }
        tstart[G_N] = nt;
        *ntiles = nt;
    }
    __syncthreads();
    for (int i = t; i < NB * G_N; i += 256) boff[i] = sbc[i] + st[i % G_N];
    int nt = tstart[G_N];
    for (int i = t; i < MAXT; i += 256) {
        int gd = 0, r0 = 0, nr = 0;
        if (i < nt) {
            int g = 0;
            while (g < G_N - 1 && i >= tstart[g + 1]) g++;
            int k = i - tstart[g];
            r0 = st[g] + k * TBM;
            int rem = tot[g] - k * TBM;
            nr = rem < TBM ? rem : TBM;
            gd = g;
        }
        desc[i * 3 + 0] = gd; desc[i * 3 + 1] = r0; desc[i * 3 + 2] = nr;
    }
}

// ---------- sort: stable scatter ----------
__global__ void k_scatter(const int* __restrict__ idx, const int* __restrict__ boff,
                          int* __restrict__ perm) {
    __shared__ int wcnt[4][G_N];
    __shared__ int base[G_N];
    int t = threadIdx.x, w = t >> 6, l = t & 63;
    int e = blockIdx.x * CHUNK + t;
    int g = idx[e];
    int rank = 0;
    for (int gg = 0; gg < G_N; gg++) {
        unsigned long long m = __ballot(g == gg);
        if (g == gg) rank = __popcll(m & ((1ull << l) - 1ull));
        if (l == 0) wcnt[w][gg] = __popcll(m);
    }
    if (t < G_N) base[t] = boff[blockIdx.x * G_N + t];
    __syncthreads();
    int off = base[g] + rank;
    for (int ww = 0; ww < w; ww++) off += wcnt[ww][g];
    perm[off] = e;
}

// ---------- weight transpose+convert: [K][N] f32 -> [N][K] bf16 ----------
__global__ void k_trans(const float* __restrict__ src, unsigned short* __restrict__ dst,
                        int K, int N, long srcStrideZ, long dstStrideZ) {
    __shared__ float tile[32][33];
    const float* s = src + (long)blockIdx.z * srcStrideZ;
    unsigned short* d = dst + (long)blockIdx.z * dstStrideZ;
    int n0 = blockIdx.x * 32, k0 = blockIdx.y * 32;
    int tx = threadIdx.x & 31, ty = threadIdx.x >> 5; // ty in 0..7
    for (int r = 0; r < 32; r += 8)
        tile[ty + r][tx] = s[(long)(k0 + ty + r) * N + n0 + tx];
    __syncthreads();
    for (int r = 0; r < 32; r += 8)
        d[(long)(n0 + ty + r) * K + k0 + tx] = f2bf(tile[tx][ty + r]);
}

// ---------- GEMM1: grouped, gathered A (fp32), no-LDS streaming, sigmoid ----------
// One block = one 64-row group tile; wave w computes rows x N[w*64, w*64+64).
// All frag addresses loop-invariant; K via immediate offsets; register dbuf.
__global__ __launch_bounds__(256) void k_gemm1(
    const float* __restrict__ state, const unsigned short* __restrict__ w1t,
    const float* __restrict__ b1, const int* __restrict__ perm,
    const int* __restrict__ desc, unsigned short* __restrict__ h1) {
    int td = blockIdx.x;
    int g = desc[td * 3 + 0];
    int row0 = desc[td * 3 + 1];
    int nrows = desc[td * 3 + 2];
    if (nrows == 0) return;

    int t = threadIdx.x, w = t >> 6, l = t & 63;
    int lrow = l & 15, q = l >> 4;
    int wn = w * 64;

    // A frag bases: frag i covers rows m = i*16 + lrow, k-slice q*8 (floats)
    const float* abase[4];
#pragma unroll
    for (int i = 0; i < 4; i++) {
        int pr = row0 + i * 16 + lrow;
        if (pr >= B_N) pr = B_N - 1;          // tail clamp (masked at store)
        long srow = perm[pr];
        abase[i] = state + srow * IN_N + q * 8;
    }
    // B frag bases: frag j covers n = wn + j*16 + lrow, same k-slice (bf16)
    const unsigned short* bbase[4];
#pragma unroll
    for (int j = 0; j < 4; j++) {
        int n = wn + j * 16 + lrow;
        bbase[j] = w1t + ((long)g * F_N + n) * IN_N + q * 8;
    }

    f32x4 acc[4][4];
#pragma unroll
    for (int i = 0; i < 4; i++)
#pragma unroll
        for (int j = 0; j < 4; j++) acc[i][j] = (f32x4){0.f, 0.f, 0.f, 0.f};

    uint4 a0[2][4], a1[2][4], bv[2][4];
#define LD1(buf, k0)                                                         \
    {                                                                        \
        _Pragma("unroll") for (int i = 0; i < 4; i++) {                      \
            a0[buf][i] = *(const uint4*)(abase[i] + (k0));                   \
            a1[buf][i] = *(const uint4*)(abase[i] + (k0) + 4);               \
        }                                                                    \
        _Pragma("unroll") for (int j = 0; j < 4; j++)                        \
            bv[buf][j] = *(const uint4*)(bbase[j] + (k0));                   \
    }

    LD1(0, 0);
#pragma unroll
    for (int kk = 0; kk < 16; kk++) {
        int cur = kk & 1, nxt = cur ^ 1;
        if (kk < 15) LD1(nxt, (kk + 1) * 32);
        bf16x8 af[4], bfv[4];
#pragma unroll
        for (int i = 0; i < 4; i++) af[i] = cvt8(a0[cur][i], a1[cur][i]);
#pragma unroll
        for (int j = 0; j < 4; j++) { union { uint4 u; bf16x8 b; } c; c.u = bv[cur][j]; bfv[j] = c.b; }
#pragma unroll
        for (int i = 0; i < 4; i++)
#pragma unroll
            for (int j = 0; j < 4; j++)
                acc[i][j] = __builtin_amdgcn_mfma_f32_16x16x32_bf16(af[i], bfv[j], acc[i][j], 0, 0, 0);
    }
#undef LD1

#pragma unroll
    for (int i = 0; i < 4; i++) {
        int mbase = i * 16 + q * 4;
#pragma unroll
        for (int j = 0; j < 4; j++) {
            int n = wn + j * 16 + lrow;
            float bias = b1[g * F_N + n];
#pragma unroll
            for (int r = 0; r < 4; r++) {
                int m = mbase + r;
                if (m < nrows) {
                    float v = acc[i][j][r] + bias;
                    float s = 1.0f / (1.0f + __expf(-v));
                    h1[(long)(row0 + m) * F_N + n] = f2bf(s);
                }
            }
        }
    }
}

// ---------- GEMM2: H1 @ W2 + b2, relu, no-LDS streaming ----------
__global__ __launch_bounds__(256) void k_gemm2(
    const unsigned short* __restrict__ h1, const unsigned short* __restrict__ w2t,
    const float* __restrict__ b2, unsigned short* __restrict__ hf) {
    int row0 = blockIdx.x * TBM;
    int t = threadIdx.x, w = t >> 6, l = t & 63;
    int lrow = l & 15, q = l >> 4;
    int wn = w * 64;

    const unsigned short* abase[4];
#pragma unroll
    for (int i = 0; i < 4; i++)
        abase[i] = h1 + (long)(row0 + i * 16 + lrow) * F_N + q * 8;
    const unsigned short* bbase[4];
#pragma unroll
    for (int j = 0; j < 4; j++)
        bbase[j] = w2t + (long)(wn + j * 16 + lrow) * F_N + q * 8;

    f32x4 acc[4][4];
#pragma unroll
    for (int i = 0; i < 4; i++)
#pragma unroll
        for (int j = 0; j < 4; j++) acc[i][j] = (f32x4){0.f, 0.f, 0.f, 0.f};

    uint4 av[2][4], bv[2][4];
#define LD2(buf, k0)                                                         \
    {                                                                        \
        _Pragma("unroll") for (int i = 0; i < 4; i++)                        \
            av[buf][i] = *(const uint4*)(abase[i] + (k0));                   \
        _Pragma("unroll") for (int j = 0; j < 4; j++)                        \
            bv[buf][j] = *(const uint4*)(bbase[j] + (k0));                   \
    }

    LD2(0, 0);
#pragma unroll
    for (int kk = 0; kk < 8; kk++) {
        int cur = kk & 1, nxt = cur ^ 1;
        if (kk < 7) LD2(nxt, (kk + 1) * 32);
        bf16x8 af[4], bfv[4];
#pragma unroll
        for (int i = 0; i < 4; i++) { union { uint4 u; bf16x8 b; } c; c.u = av[cur][i]; af[i] = c.b; }
#pragma unroll
        for (int j = 0; j < 4; j++) { union { uint4 u; bf16x8 b; } c; c.u = bv[cur][j]; bfv[j] = c.b; }
#pragma unroll
        for (int i = 0; i < 4; i++)
#pragma unroll
            for (int j = 0; j < 4; j++)
                acc[i][j] = __builtin_amdgcn_mfma_f32_16x16x32_bf16(af[i], bfv[j], acc[i][j], 0, 0, 0);
    }
#undef LD2

#pragma unroll
    for (int i = 0; i < 4; i++) {
        int mbase = i * 16 + q * 4;
#pragma unroll
        for (int j = 0; j < 4; j++) {
            int n = wn + j * 16 + lrow;
            float bias = b2[n];
#pragma unroll
            for (int r = 0; r < 4; r++) {
                int m = mbase + r;
                float v = acc[i][j][r] + bias;
                v = fmaxf(v, 0.0f);
                hf[(long)(row0 + m) * F_N + n] = f2bf(v);
            }
        }
    }
}

// ---------- final: out[s] = tanh(dot(hf[s,:], Wq[idx[s],:,action[s]]) + bq[idx[s],action[s]]) ----------
__global__ void k_final(const unsigned short* __restrict__ hf, const float* __restrict__ wq,
                        const float* __restrict__ bqv, const int* __restrict__ idx,
                        const int* __restrict__ action, float* __restrict__ out) {
    int t = threadIdx.x, w = t >> 6, l = t & 63;
    long s = (long)blockIdx.x * 4 + w;
    int g = idx[s], a = action[s];
    const unsigned short* hp = hf + s * F_N + l * 4;
    ushort4 hv = *(const ushort4*)hp;
    const float* wp = wq + ((long)g * F_N + l * 4) * O_N + a;
    float sum = bf2f(hv.x) * wp[0] + bf2f(hv.y) * wp[O_N] +
                bf2f(hv.z) * wp[2 * O_N] + bf2f(hv.w) * wp[3 * O_N];
#pragma unroll
    for (int o = 32; o > 0; o >>= 1) sum += __shfl_down(sum, o, 64);
    if (l == 0) out[s] = tanhf(sum + bqv[g * O_N + a]);
}

extern "C" void kernel_launch(void* const* d_in, const int* in_sizes, int n_in,
                              void* d_out, int out_size, void* d_ws, size_t ws_size,
                              hipStream_t stream) {
    const float* state  = (const float*)d_in[0];
    const int*   action = (const int*)d_in[1];
    const int*   idx    = (const int*)d_in[2];
    const float* W1     = (const float*)d_in[3];
    const float* b1     = (const float*)d_in[4];
    const float* W2     = (const float*)d_in[5];
    const float* b2     = (const float*)d_in[6];
    const float* Wq     = (const float*)d_in[7];
    const float* bq     = (const float*)d_in[8];
    float* out = (float*)d_out;

    char* ws = (char*)d_ws;
    int* bc      = (int*)(ws + WS_BC);
    int* boff    = (int*)(ws + WS_BOFF);
    int* ntiles  = (int*)(ws + WS_NTILES);
    int* desc    = (int*)(ws + WS_DESC);
    unsigned short* W1t = (unsigned short*)(ws + WS_W1T);
    unsigned short* W2t = (unsigned short*)(ws + WS_W2T);
    int* perm    = (int*)(ws + WS_PERM);
    unsigned short* H1  = (unsigned short*)(ws + WS_H1);
    unsigned short* HF  = (unsigned short*)(ws + WS_HF);

    k_hist<<<NB, CHUNK, 0, stream>>>(idx, bc);
    k_prefix<<<1, 256, 0, stream>>>(bc, boff, ntiles, desc);
    k_scatter<<<NB, CHUNK, 0, stream>>>(idx, boff, perm);
    k_trans<<<dim3(F_N / 32, IN_N / 32, G_N), 256, 0, stream>>>(W1, W1t, IN_N, F_N,
                                                                (long)IN_N * F_N, (long)F_N * IN_N);
    k_trans<<<dim3(F_N / 32, F_N / 32, 1), 256, 0, stream>>>(W2, W2t, F_N, F_N, 0, 0);
    k_gemm1<<<MAXT, 256, 0, stream>>>(state, W1t, b1, perm, desc, H1);
    k_gemm2<<<B_N / TBM, 256, 0, stream>>>(H1, W2t, b2, HF);
    k_final<<<B_N / 4, 256, 0, stream>>>(HF, Wq, bq, idx, action, out);
}

// Round 6
// 326.983 us; speedup vs baseline: 1.1695x; 1.1695x over previous
//
#include <hip/hip_runtime.h>
#include <math.h>

// Problem constants
#define B_N 65536
#define G_N 6
#define IN_N 512
#define F_N 256
#define O_N 18

// Sort constants
#define NB 256     // histogram blocks (B_N / 256)
#define CHUNK 256

// Fused kernel tiling: 32 sorted rows per block, full N=256, 8 waves of 32x32.
#define TBM 32
#define MAXT 2054   // 65536/32 + G

typedef __bf16 bf16x8 __attribute__((ext_vector_type(8)));
typedef float f32x4 __attribute__((ext_vector_type(4)));

// ---- workspace layout (bytes) ----
#define WS_BC     0
#define WS_BOFF   8192
#define WS_NTILES 16448
#define WS_DESC   16512
#define WS_W1T    65536
#define WS_W2T    1703936
#define WS_PERM   2097152

__device__ __forceinline__ unsigned short f2bf(float f) {
    union { float f; unsigned u; } a; a.f = f;
    unsigned r = a.u + 0x7fffu + ((a.u >> 16) & 1u);
    return (unsigned short)(r >> 16);
}
__device__ __forceinline__ unsigned pack2(float a, float b) {
    return (unsigned)f2bf(a) | ((unsigned)f2bf(b) << 16);
}

// ---------- sort: histogram ----------
__global__ void k_hist(const int* __restrict__ idx, int* __restrict__ bc) {
    __shared__ int cnt[G_N];
    int t = threadIdx.x;
    if (t < G_N) cnt[t] = 0;
    __syncthreads();
    int e = blockIdx.x * CHUNK + t;
    atomicAdd(&cnt[idx[e]], 1);
    __syncthreads();
    if (t < G_N) bc[blockIdx.x * G_N + t] = cnt[t];
}

// ---------- sort: prefix + tile descriptors (single block, parallel scan) ----------
__global__ void k_prefix(const int* __restrict__ bc, int* __restrict__ boff,
                         int* __restrict__ ntiles, int* __restrict__ desc) {
    __shared__ int sbc[NB * G_N];   // 6 KB
    __shared__ int tot[G_N], st[G_N];
    __shared__ int tstart[G_N + 1];
    int t = threadIdx.x;
    for (int i = t; i < NB * G_N; i += 256) sbc[i] = bc[i];
    __syncthreads();
    int w = t >> 6, l = t & 63;
    for (int g = w; g < G_N; g += 4) {
        int v[4]; int s = 0;
#pragma unroll
        for (int j = 0; j < 4; j++) { v[j] = sbc[(l * 4 + j) * G_N + g]; s += v[j]; }
        int inc = s;
#pragma unroll
        for (int o = 1; o < 64; o <<= 1) { int x = __shfl_up(inc, o, 64); if (l >= o) inc += x; }
        int run = inc - s;   // exclusive prefix
        if (l == 63) tot[g] = inc;
#pragma unroll
        for (int j = 0; j < 4; j++) { sbc[(l * 4 + j) * G_N + g] = run; run += v[j]; }
    }
    __syncthreads();
    if (t == 0) {
        int acc = 0;
        for (int g = 0; g < G_N; g++) { st[g] = acc; acc += tot[g]; }
        int nt = 0;
        for (int g = 0; g < G_N; g++) { tstart[g] = nt; nt += (tot[g] + TBM - 1) / TBM; }
        tstart[G_N] = nt;
        *ntiles = nt;
    }
    __syncthreads();
    for (int i = t; i < NB * G_N; i += 256) boff[i] = sbc[i] + st[i % G_N];
    int nt = tstart[G_N];
    for (int i = t; i < MAXT; i += 256) {
        int gd = 0, r0 = 0, nr = 0;
        if (i < nt) {
            int g = 0;
            while (g < G_N - 1 && i >= tstart[g + 1]) g++;
            int k = i - tstart[g];
            r0 = st[g] + k * TBM;
            int rem = tot[g] - k * TBM;
            nr = rem < TBM ? rem : TBM;
            gd = g;
        }
        desc[i * 3 + 0] = gd; desc[i * 3 + 1] = r0; desc[i * 3 + 2] = nr;
    }
}

// ---------- sort: stable scatter ----------
__global__ void k_scatter(const int* __restrict__ idx, const int* __restrict__ boff,
                          int* __restrict__ perm) {
    __shared__ int wcnt[4][G_N];
    __shared__ int base[G_N];
    int t = threadIdx.x, w = t >> 6, l = t & 63;
    int e = blockIdx.x * CHUNK + t;
    int g = idx[e];
    int rank = 0;
    for (int gg = 0; gg < G_N; gg++) {
        unsigned long long m = __ballot(g == gg);
        if (g == gg) rank = __popcll(m & ((1ull << l) - 1ull));
        if (l == 0) wcnt[w][gg] = __popcll(m);
    }
    if (t < G_N) base[t] = boff[blockIdx.x * G_N + t];
    __syncthreads();
    int off = base[g] + rank;
    for (int ww = 0; ww < w; ww++) off += wcnt[ww][g];
    perm[off] = e;
}

// ---------- weight transpose+convert: [K][N] f32 -> [N][K] bf16 ----------
__global__ void k_trans(const float* __restrict__ src, unsigned short* __restrict__ dst,
                        int K, int N, long srcStrideZ, long dstStrideZ) {
    __shared__ float tile[32][33];
    const float* s = src + (long)blockIdx.z * srcStrideZ;
    unsigned short* d = dst + (long)blockIdx.z * dstStrideZ;
    int n0 = blockIdx.x * 32, k0 = blockIdx.y * 32;
    int tx = threadIdx.x & 31, ty = threadIdx.x >> 5; // ty in 0..7
    for (int r = 0; r < 32; r += 8)
        tile[ty + r][tx] = s[(long)(k0 + ty + r) * N + n0 + tx];
    __syncthreads();
    for (int r = 0; r < 32; r += 8)
        d[(long)(n0 + ty + r) * K + k0 + tx] = f2bf(tile[tx][ty + r]);
}

// ---------- fused: expert GEMM -> sigmoid -> shared GEMM -> relu -> Q-head dot -> tanh ----------
// Block: 32 sorted positions pos = row0..row0+31 (one game tile), full N=256.
// 512 threads = 8 waves, wave w owns n-slice [w*32, w*32+32).
// Features come from state[perm[pos]]; BUT (reference quirk) the Q-head uses
// idx[pos]/action[pos] (ORIGINAL-order arrays at the sorted position) and the
// output lands at position pos. A staged ONCE to LDS (bf16, XOR-swizzled);
// B frags streamed per-lane from L2. No barrier inside K-loops.
__global__ __launch_bounds__(512, 4) void k_fused(
    const float* __restrict__ state, const unsigned short* __restrict__ w1t,
    const unsigned short* __restrict__ w2t,
    const float* __restrict__ b1, const float* __restrict__ b2,
    const float* __restrict__ wq, const float* __restrict__ bqv,
    const int* __restrict__ action, const int* __restrict__ idx,
    const int* __restrict__ perm,
    const int* __restrict__ desc, float* __restrict__ out) {
    int td = blockIdx.x;
    int g = desc[td * 3 + 0], row0 = desc[td * 3 + 1], nr = desc[td * 3 + 2];
    if (nr == 0) return;

    __shared__ __align__(16) unsigned short smA[32 * 512];   // 32 KB; reused as H1 (32x256) in phase 2
    __shared__ float partial[32][9];
    __shared__ int gq[32], actv[32];
    unsigned short* smH = smA;   // alias (A dead after phase 1)

    int t = threadIdx.x, w = t >> 6, l = t & 63;
    int lrow = l & 15, q = l >> 4;

    if (t < 32) {
        int pos = row0 + t; if (pos > B_N - 1) pos = B_N - 1;
        gq[t] = idx[pos];        // ORIGINAL-order idx at sorted position (reference quirk)
        actv[t] = action[pos];   // ORIGINAL-order action at sorted position
    }

    // ---- stage A once: 16 threads/row, each 8x(float4 load + cvt + ds_write_b64) ----
    {
        int m = t >> 4, s = t & 15;
        int pr = row0 + m; if (pr > B_N - 1) pr = B_N - 1;
        const float* src = state + (long)perm[pr] * IN_N + s * 4;
        int cb = s >> 1, h = s & 1, mx = m & 7;
        char* rowbase = (char*)smA + m * 1024 + h * 8;
#pragma unroll
        for (int j = 0; j < 8; j++) {
            float4 v = *(const float4*)(src + j * 64);
            uint2 p = { pack2(v.x, v.y), pack2(v.z, v.w) };
            int c = (cb + j * 8) ^ mx;
            *(uint2*)(rowbase + c * 16) = p;
        }
    }
    __syncthreads();

    // ---- phase 1: H1 = sigmoid(A @ W1[g] + b1[g]), K=512, no barriers ----
    const unsigned short* bb = w1t + ((long)g * F_N + w * 32) * IN_N;
    const unsigned short* bp0 = bb + (long)lrow * IN_N + q * 8;
    const unsigned short* bp1 = bb + (long)(16 + lrow) * IN_N + q * 8;
    int x0 = lrow & 7;   // (m&7) for both m=lrow and m=16+lrow
    const char* ar0 = (const char*)smA + lrow * 1024;
    const char* ar1 = (const char*)smA + (16 + lrow) * 1024;

    f32x4 acc[2][2];
#pragma unroll
    for (int i = 0; i < 2; i++)
#pragma unroll
        for (int j = 0; j < 2; j++) acc[i][j] = (f32x4){0.f, 0.f, 0.f, 0.f};

#pragma unroll
    for (int kf = 0; kf < 16; kf++) {
        int c = ((kf * 4 + q) ^ x0) * 16;
        bf16x8 a0 = *(const bf16x8*)(ar0 + c);
        bf16x8 a1 = *(const bf16x8*)(ar1 + c);
        bf16x8 b0 = *(const bf16x8*)(bp0 + kf * 32);
        bf16x8 b1 = *(const bf16x8*)(bp1 + kf * 32);
        acc[0][0] = __builtin_amdgcn_mfma_f32_16x16x32_bf16(a0, b0, acc[0][0], 0, 0, 0);
        acc[1][0] = __builtin_amdgcn_mfma_f32_16x16x32_bf16(a1, b0, acc[1][0], 0, 0, 0);
        acc[0][1] = __builtin_amdgcn_mfma_f32_16x16x32_bf16(a0, b1, acc[0][1], 0, 0, 0);
        acc[1][1] = __builtin_amdgcn_mfma_f32_16x16x32_bf16(a1, b1, acc[1][1], 0, 0, 0);
    }
    __syncthreads();   // A reads done; smA region becomes H1

    // ---- epilogue 1: sigmoid -> bf16 -> swizzled LDS H1[32][256] ----
    {
        int col0 = w * 32 + lrow;
#pragma unroll
        for (int j = 0; j < 2; j++) {
            int col = col0 + j * 16;
            float bias = b1[g * F_N + col];
            int cc = col >> 3, cb2 = (col & 7) * 2;
#pragma unroll
            for (int i = 0; i < 2; i++)
#pragma unroll
                for (int r = 0; r < 4; r++) {
                    int row = q * 4 + r + 16 * i;
                    float v = acc[i][j][r] + bias;
                    float sg = 1.0f / (1.0f + __expf(-v));
                    int c = cc ^ (row & 7);
                    *(unsigned short*)((char*)smH + row * 512 + c * 16 + cb2) = f2bf(sg);
                }
        }
    }
    __syncthreads();

    // ---- phase 2: HF = relu(H1 @ W2 + b2), K=256, no barriers ----
    const unsigned short* cp0 = w2t + (long)(w * 32 + lrow) * F_N + q * 8;
    const unsigned short* cp1 = cp0 + 16 * F_N;
    const char* hr0 = (const char*)smH + lrow * 512;
    const char* hr1 = (const char*)smH + (16 + lrow) * 512;

    f32x4 acc2[2][2];
#pragma unroll
    for (int i = 0; i < 2; i++)
#pragma unroll
        for (int j = 0; j < 2; j++) acc2[i][j] = (f32x4){0.f, 0.f, 0.f, 0.f};

#pragma unroll
    for (int kf = 0; kf < 8; kf++) {
        int c = ((kf * 4 + q) ^ x0) * 16;
        bf16x8 a0 = *(const bf16x8*)(hr0 + c);
        bf16x8 a1 = *(const bf16x8*)(hr1 + c);
        bf16x8 b0 = *(const bf16x8*)(cp0 + kf * 32);
        bf16x8 b1 = *(const bf16x8*)(cp1 + kf * 32);
        acc2[0][0] = __builtin_amdgcn_mfma_f32_16x16x32_bf16(a0, b0, acc2[0][0], 0, 0, 0);
        acc2[1][0] = __builtin_amdgcn_mfma_f32_16x16x32_bf16(a1, b0, acc2[1][0], 0, 0, 0);
        acc2[0][1] = __builtin_amdgcn_mfma_f32_16x16x32_bf16(a0, b1, acc2[0][1], 0, 0, 0);
        acc2[1][1] = __builtin_amdgcn_mfma_f32_16x16x32_bf16(a1, b1, acc2[1][1], 0, 0, 0);
    }

    // ---- final: per-row dot with Wq[idx[pos]][:,action[pos]], wave-partial reduce ----
    {
        int col0 = w * 32 + lrow;
        float bias0 = b2[col0], bias1 = b2[col0 + 16];
#pragma unroll
        for (int i = 0; i < 2; i++)
#pragma unroll
            for (int r = 0; r < 4; r++) {
                int row = q * 4 + r + 16 * i;
                int a = actv[row];
                int gh = gq[row];
                const float* wp = wq + ((long)gh * F_N + col0) * O_N + a;
                float v0 = fmaxf(acc2[i][0][r] + bias0, 0.0f);
                float v1 = fmaxf(acc2[i][1][r] + bias1, 0.0f);
                float s = v0 * wp[0] + v1 * wp[16 * O_N];
                s += __shfl_xor(s, 1, 64);
                s += __shfl_xor(s, 2, 64);
                s += __shfl_xor(s, 4, 64);
                s += __shfl_xor(s, 8, 64);
                if (lrow == 0) partial[row][w] = s;
            }
    }
    __syncthreads();
    if (t < nr) {
        float s = 0.f;
#pragma unroll
        for (int ww = 0; ww < 8; ww++) s += partial[t][ww];
        out[row0 + t] = tanhf(s + bqv[gq[t] * O_N + actv[t]]);
    }
}

extern "C" void kernel_launch(void* const* d_in, const int* in_sizes, int n_in,
                              void* d_out, int out_size, void* d_ws, size_t ws_size,
                              hipStream_t stream) {
    const float* state  = (const float*)d_in[0];
    const int*   action = (const int*)d_in[1];
    const int*   idx    = (const int*)d_in[2];
    const float* W1     = (const float*)d_in[3];
    const float* b1     = (const float*)d_in[4];
    const float* W2     = (const float*)d_in[5];
    const float* b2     = (const float*)d_in[6];
    const float* Wq     = (const float*)d_in[7];
    const float* bq     = (const float*)d_in[8];
    float* out = (float*)d_out;

    char* ws = (char*)d_ws;
    int* bc      = (int*)(ws + WS_BC);
    int* boff    = (int*)(ws + WS_BOFF);
    int* ntiles  = (int*)(ws + WS_NTILES);
    int* desc    = (int*)(ws + WS_DESC);
    unsigned short* W1t = (unsigned short*)(ws + WS_W1T);
    unsigned short* W2t = (unsigned short*)(ws + WS_W2T);
    int* perm    = (int*)(ws + WS_PERM);

    k_hist<<<NB, CHUNK, 0, stream>>>(idx, bc);
    k_prefix<<<1, 256, 0, stream>>>(bc, boff, ntiles, desc);
    k_scatter<<<NB, CHUNK, 0, stream>>>(idx, boff, perm);
    k_trans<<<dim3(F_N / 32, IN_N / 32, G_N), 256, 0, stream>>>(W1, W1t, IN_N, F_N,
                                                                (long)IN_N * F_N, (long)F_N * IN_N);
    k_trans<<<dim3(F_N / 32, F_N / 32, 1), 256, 0, stream>>>(W2, W2t, F_N, F_N, 0, 0);
    k_fused<<<MAXT, 512, 0, stream>>>(state, W1t, W2t, b1, b2, Wq, bq,
                                      action, idx, perm, desc, out);
}

// Round 7
// 267.242 us; speedup vs baseline: 1.4310x; 1.2235x over previous
//
#include <hip/hip_runtime.h>
#include <math.h>

// Problem constants
#define B_N 65536
#define G_N 6
#define IN_N 512
#define F_N 256
#define O_N 18

// Sort constants
#define NB 256     // histogram blocks (B_N / 256)
#define CHUNK 256

// Fused kernel tiling: 64 sorted rows per block, full N=256, 8 waves.
#define TBM 64
#define MAXT 1030   // 65536/64 + G

typedef __bf16 bf16x8 __attribute__((ext_vector_type(8)));
typedef float f32x4 __attribute__((ext_vector_type(4)));

// ---- workspace layout (bytes) ----
#define WS_BC     0
#define WS_BOFF   8192
#define WS_NTILES 16448
#define WS_DESC   16512
#define WS_W1F    65536                         // 6 * 256KB = 1572864
#define WS_W2F    (WS_W1F + 1572864)            // 128KB
#define WS_WQT    (WS_W2F + 131072)             // 6*18*256*4 = 110592
#define WS_PERM   4194304

__device__ __forceinline__ unsigned short f2bf(float f) {
    union { float f; unsigned u; } a; a.f = f;
    unsigned r = a.u + 0x7fffu + ((a.u >> 16) & 1u);
    return (unsigned short)(r >> 16);
}
__device__ __forceinline__ unsigned pack2(float a, float b) {
    return (unsigned)f2bf(a) | ((unsigned)f2bf(b) << 16);
}
__device__ __forceinline__ bf16x8 asbf(uint4 u) {
    union { uint4 u; bf16x8 b; } c; c.u = u; return c.b;
}

// ---------- sort: histogram ----------
__global__ void k_hist(const int* __restrict__ idx, int* __restrict__ bc) {
    __shared__ int cnt[G_N];
    int t = threadIdx.x;
    if (t < G_N) cnt[t] = 0;
    __syncthreads();
    int e = blockIdx.x * CHUNK + t;
    atomicAdd(&cnt[idx[e]], 1);
    __syncthreads();
    if (t < G_N) bc[blockIdx.x * G_N + t] = cnt[t];
}

// ---------- sort: prefix + tile descriptors (single block, parallel scan) ----------
__global__ void k_prefix(const int* __restrict__ bc, int* __restrict__ boff,
                         int* __restrict__ ntiles, int* __restrict__ desc) {
    __shared__ int sbc[NB * G_N];   // 6 KB
    __shared__ int tot[G_N], st[G_N];
    __shared__ int tstart[G_N + 1];
    int t = threadIdx.x;
    for (int i = t; i < NB * G_N; i += 256) sbc[i] = bc[i];
    __syncthreads();
    int w = t >> 6, l = t & 63;
    for (int g = w; g < G_N; g += 4) {
        int v[4]; int s = 0;
#pragma unroll
        for (int j = 0; j < 4; j++) { v[j] = sbc[(l * 4 + j) * G_N + g]; s += v[j]; }
        int inc = s;
#pragma unroll
        for (int o = 1; o < 64; o <<= 1) { int x = __shfl_up(inc, o, 64); if (l >= o) inc += x; }
        int run = inc - s;   // exclusive prefix
        if (l == 63) tot[g] = inc;
#pragma unroll
        for (int j = 0; j < 4; j++) { sbc[(l * 4 + j) * G_N + g] = run; run += v[j]; }
    }
    __syncthreads();
    if (t == 0) {
        int acc = 0;
        for (int g = 0; g < G_N; g++) { st[g] = acc; acc += tot[g]; }
        int nt = 0;
        for (int g = 0; g < G_N; g++) { tstart[g] = nt; nt += (tot[g] + TBM - 1) / TBM; }
        tstart[G_N] = nt;
        *ntiles = nt;
    }
    __syncthreads();
    for (int i = t; i < NB * G_N; i += 256) boff[i] = sbc[i] + st[i % G_N];
    int nt = tstart[G_N];
    for (int i = t; i < MAXT; i += 256) {
        int gd = 0, r0 = 0, nr = 0;
        if (i < nt) {
            int g = 0;
            while (g < G_N - 1 && i >= tstart[g + 1]) g++;
            int k = i - tstart[g];
            r0 = st[g] + k * TBM;
            int rem = tot[g] - k * TBM;
            nr = rem < TBM ? rem : TBM;
            gd = g;
        }
        desc[i * 3 + 0] = gd; desc[i * 3 + 1] = r0; desc[i * 3 + 2] = nr;
    }
}

// ---------- sort: stable scatter ----------
__global__ void k_scatter(const int* __restrict__ idx, const int* __restrict__ boff,
                          int* __restrict__ perm) {
    __shared__ int wcnt[4][G_N];
    __shared__ int base[G_N];
    int t = threadIdx.x, w = t >> 6, l = t & 63;
    int e = blockIdx.x * CHUNK + t;
    int g = idx[e];
    int rank = 0;
    for (int gg = 0; gg < G_N; gg++) {
        unsigned long long m = __ballot(g == gg);
        if (g == gg) rank = __popcll(m & ((1ull << l) - 1ull));
        if (l == 0) wcnt[w][gg] = __popcll(m);
    }
    if (t < G_N) base[t] = boff[blockIdx.x * G_N + t];
    __syncthreads();
    int off = base[g] + rank;
    for (int ww = 0; ww < w; ww++) off += wcnt[ww][g];
    perm[off] = e;
}

// ---------- weight pack: [K][N=256] fp32 -> fragment-major bf16 ----------
// dst layout: [g][w(8)][kf(K/32)][frag(2)][lane(64)][8 shorts]; lane l holds
// n = w*32 + frag*16 + (l&15), k = kf*32 + (l>>4)*8 + j.
__global__ void k_pack(const float* __restrict__ src, unsigned short* __restrict__ dst,
                       long srcZ, long dstZ) {
    int kf = blockIdx.x, w = blockIdx.y, g = blockIdx.z;
    int kfTot = gridDim.x;
    int f = threadIdx.x >> 6, l = threadIdx.x & 63;
    int lrow = l & 15, q = l >> 4;
    int n = w * 32 + f * 16 + lrow;
    int k0 = kf * 32 + q * 8;
    const float* s = src + (long)g * srcZ + (long)k0 * F_N + n;
    unsigned o[4];
#pragma unroll
    for (int j = 0; j < 4; j++)
        o[j] = pack2(s[(2 * j) * F_N], s[(2 * j + 1) * F_N]);
    unsigned short* d = dst + (long)g * dstZ +
        ((((long)w * kfTot + kf) * 2 + f) * 64 + l) * 8;
    uint4 v = { o[0], o[1], o[2], o[3] };
    *(uint4*)d = v;
}

// ---------- Wq transpose: [G][256][18] -> [G][18][256] fp32 ----------
__global__ void k_wqt(const float* __restrict__ wq, float* __restrict__ wqt) {
    int g = blockIdx.x, f = threadIdx.x;
#pragma unroll
    for (int o = 0; o < O_N; o++)
        wqt[((long)g * O_N + o) * F_N + f] = wq[((long)g * F_N + f) * O_N + o];
}

// ---------- fused: expert GEMM -> sigmoid -> shared GEMM -> relu -> Q-head dot -> tanh ----------
// Block: 64 sorted positions (one game tile), full N=256. 8 waves, wave w owns
// n-slice [w*32, w*32+32). A staged ONCE to LDS (bf16, XOR-swizzled). B frags
// are fragment-major packed -> every K-loop load is a coalesced 1KB wave-load.
// Reference quirk: Q-head uses idx[pos]/action[pos] (original-order arrays at
// the sorted position); output lands at position pos.
__global__ __launch_bounds__(512, 4) void k_fused(
    const float* __restrict__ state, const char* __restrict__ w1f,
    const char* __restrict__ w2f, const float* __restrict__ wqt,
    const float* __restrict__ b1, const float* __restrict__ b2,
    const float* __restrict__ bqv,
    const int* __restrict__ action, const int* __restrict__ idx,
    const int* __restrict__ perm, const int* __restrict__ desc,
    float* __restrict__ out) {
    int td = blockIdx.x;
    int g = desc[td * 3 + 0], row0 = desc[td * 3 + 1], nr = desc[td * 3 + 2];
    if (nr == 0) return;

    __shared__ __align__(16) unsigned short smA[TBM * 512];   // 64 KB; first 32 KB reused as H1
    __shared__ float partial[TBM][9];
    __shared__ int gq[TBM], actv[TBM];
    unsigned short* smH = smA;

    int t = threadIdx.x, w = t >> 6, l = t & 63;
    int lrow = l & 15, q = l >> 4;
    int x0 = lrow & 7;

    // ---- issue first B loads early (independent of LDS) ----
    const char* B1 = w1f + (((long)g * 8 + w) << 15) + l * 16;
    uint4 nb0 = *(const uint4*)(B1);
    uint4 nb1 = *(const uint4*)(B1 + 1024);

    if (t < TBM) {
        int pos = row0 + t; if (pos > B_N - 1) pos = B_N - 1;
        gq[t] = idx[pos];        // ORIGINAL-order idx at sorted position
        actv[t] = action[pos];   // ORIGINAL-order action at sorted position
    }

    // ---- stage A once: 8 threads/row, each 16x(float4 load + cvt + ds_write_b64) ----
    {
        int m = t >> 3, s = t & 7;
        int pr = row0 + m; if (pr > B_N - 1) pr = B_N - 1;
        const float* src = state + (long)perm[pr] * IN_N + s * 4;
        int cb = s >> 1, h = s & 1, mx = m & 7;
        char* rowbase = (char*)smA + m * 1024 + h * 8;
#pragma unroll
        for (int j = 0; j < 16; j++) {
            float4 v = *(const float4*)(src + j * 32);
            uint2 p = { pack2(v.x, v.y), pack2(v.z, v.w) };
            int c = (cb + j * 4) ^ mx;
            *(uint2*)(rowbase + c * 16) = p;
        }
    }
    __syncthreads();

    // ---- phase 1: H1 = sigmoid(A @ W1[g] + b1[g]), K=512, no barriers in loop ----
    const char* ar[4];
#pragma unroll
    for (int i = 0; i < 4; i++) ar[i] = (const char*)smA + (i * 16 + lrow) * 1024;

    f32x4 acc[4][2];
#pragma unroll
    for (int i = 0; i < 4; i++)
#pragma unroll
        for (int j = 0; j < 2; j++) acc[i][j] = (f32x4){0.f, 0.f, 0.f, 0.f};

#pragma unroll
    for (int kf = 0; kf < 16; kf++) {
        uint4 cb0 = nb0, cb1 = nb1;
        if (kf < 15) {
            nb0 = *(const uint4*)(B1 + (kf + 1) * 2048);
            nb1 = *(const uint4*)(B1 + (kf + 1) * 2048 + 1024);
        }
        int c = ((kf * 4 + q) ^ x0) * 16;
        bf16x8 af[4];
#pragma unroll
        for (int i = 0; i < 4; i++) af[i] = *(const bf16x8*)(ar[i] + c);
        bf16x8 b0 = asbf(cb0), b1v = asbf(cb1);
#pragma unroll
        for (int i = 0; i < 4; i++) {
            acc[i][0] = __builtin_amdgcn_mfma_f32_16x16x32_bf16(af[i], b0, acc[i][0], 0, 0, 0);
            acc[i][1] = __builtin_amdgcn_mfma_f32_16x16x32_bf16(af[i], b1v, acc[i][1], 0, 0, 0);
        }
    }
    __syncthreads();   // all A reads done; smA front 32KB becomes H1

    // ---- epilogue 1: sigmoid -> bf16 -> swizzled LDS H1[64][256] ----
    {
        int col0 = w * 32 + lrow;
#pragma unroll
        for (int j = 0; j < 2; j++) {
            int col = col0 + j * 16;
            float bias = b1[g * F_N + col];
            int cc = col >> 3, cb2 = (col & 7) * 2;
#pragma unroll
            for (int i = 0; i < 4; i++)
#pragma unroll
                for (int r = 0; r < 4; r++) {
                    int row = i * 16 + q * 4 + r;
                    float v = acc[i][j][r] + bias;
                    float sg = 1.0f / (1.0f + __expf(-v));
                    int c = cc ^ (row & 7);
                    *(unsigned short*)((char*)smH + row * 512 + c * 16 + cb2) = f2bf(sg);
                }
        }
    }
    __syncthreads();

    // ---- phase 2: HF = relu(H1 @ W2 + b2), K=256, no barriers in loop ----
    const char* B2 = w2f + ((long)w << 14) + l * 16;
    const char* hr[4];
#pragma unroll
    for (int i = 0; i < 4; i++) hr[i] = (const char*)smH + (i * 16 + lrow) * 512;

    f32x4 acc2[4][2];
#pragma unroll
    for (int i = 0; i < 4; i++)
#pragma unroll
        for (int j = 0; j < 2; j++) acc2[i][j] = (f32x4){0.f, 0.f, 0.f, 0.f};

    uint4 m0 = *(const uint4*)(B2);
    uint4 m1 = *(const uint4*)(B2 + 1024);
#pragma unroll
    for (int kf = 0; kf < 8; kf++) {
        uint4 c0 = m0, c1 = m1;
        if (kf < 7) {
            m0 = *(const uint4*)(B2 + (kf + 1) * 2048);
            m1 = *(const uint4*)(B2 + (kf + 1) * 2048 + 1024);
        }
        int c = ((kf * 4 + q) ^ x0) * 16;
        bf16x8 af[4];
#pragma unroll
        for (int i = 0; i < 4; i++) af[i] = *(const bf16x8*)(hr[i] + c);
        bf16x8 b0 = asbf(c0), b1v = asbf(c1);
#pragma unroll
        for (int i = 0; i < 4; i++) {
            acc2[i][0] = __builtin_amdgcn_mfma_f32_16x16x32_bf16(af[i], b0, acc2[i][0], 0, 0, 0);
            acc2[i][1] = __builtin_amdgcn_mfma_f32_16x16x32_bf16(af[i], b1v, acc2[i][1], 0, 0, 0);
        }
    }

    // ---- final: per-row dot with WqT[idx[pos]][action[pos]][:], wave-partial reduce ----
    {
        int col0 = w * 32 + lrow;
        float bias0 = b2[col0], bias1 = b2[col0 + 16];
#pragma unroll
        for (int i = 0; i < 4; i++)
#pragma unroll
            for (int r = 0; r < 4; r++) {
                int row = i * 16 + q * 4 + r;
                const float* wp = wqt + ((long)gq[row] * O_N + actv[row]) * F_N;
                float v0 = fmaxf(acc2[i][0][r] + bias0, 0.0f);
                float v1 = fmaxf(acc2[i][1][r] + bias1, 0.0f);
                float s = v0 * wp[col0] + v1 * wp[col0 + 16];
                s += __shfl_xor(s, 1, 64);
                s += __shfl_xor(s, 2, 64);
                s += __shfl_xor(s, 4, 64);
                s += __shfl_xor(s, 8, 64);
                if (lrow == 0) partial[row][w] = s;
            }
    }
    __syncthreads();
    if (t < TBM && t < nr) {
        float s = 0.f;
#pragma unroll
        for (int ww = 0; ww < 8; ww++) s += partial[t][ww];
        out[row0 + t] = tanhf(s + bqv[gq[t] * O_N + actv[t]]);
    }
}

extern "C" void kernel_launch(void* const* d_in, const int* in_sizes, int n_in,
                              void* d_out, int out_size, void* d_ws, size_t ws_size,
                              hipStream_t stream) {
    const float* state  = (const float*)d_in[0];
    const int*   action = (const int*)d_in[1];
    const int*   idx    = (const int*)d_in[2];
    const float* W1     = (const float*)d_in[3];
    const float* b1     = (const float*)d_in[4];
    const float* W2     = (const float*)d_in[5];
    const float* b2     = (const float*)d_in[6];
    const float* Wq     = (const float*)d_in[7];
    const float* bq     = (const float*)d_in[8];
    float* out = (float*)d_out;

    char* ws = (char*)d_ws;
    int* bc      = (int*)(ws + WS_BC);
    int* boff    = (int*)(ws + WS_BOFF);
    int* ntiles  = (int*)(ws + WS_NTILES);
    int* desc    = (int*)(ws + WS_DESC);
    unsigned short* W1f = (unsigned short*)(ws + WS_W1F);
    unsigned short* W2f = (unsigned short*)(ws + WS_W2F);
    float* WqT   = (float*)(ws + WS_WQT);
    int* perm    = (int*)(ws + WS_PERM);

    k_hist<<<NB, CHUNK, 0, stream>>>(idx, bc);
    k_prefix<<<1, 256, 0, stream>>>(bc, boff, ntiles, desc);
    k_scatter<<<NB, CHUNK, 0, stream>>>(idx, boff, perm);
    k_pack<<<dim3(IN_N / 32, 8, G_N), 128, 0, stream>>>(W1, W1f,
                                                        (long)IN_N * F_N, (long)IN_N * F_N);
    k_pack<<<dim3(F_N / 32, 8, 1), 128, 0, stream>>>(W2, W2f, 0, 0);
    k_wqt<<<G_N, 256, 0, stream>>>(Wq, WqT);
    k_fused<<<MAXT, 512, 0, stream>>>(state, (const char*)W1f, (const char*)W2f, WqT,
                                      b1, b2, bq, action, idx, perm, desc, out);
}